// Round 1
// baseline (11506.615 us; speedup 1.0000x reference)
//
#include <hip/hip_runtime.h>

#define NTH 256
#define NBOX 16384
#define NCLSIN 91
#define NCLS 90
#define MAXSEL 100
#define TOPK 200
#define NEGV (-1e30f)
#define NEGH (-1e29f)

// monotone fp32 -> uint32 mapping (order-preserving for all non-NaN)
__device__ __forceinline__ unsigned int fmap(float f) {
    unsigned int u = __float_as_uint(f);
    return (u & 0x80000000u) ? ~u : (u | 0x80000000u);
}
__device__ __forceinline__ float funmap(unsigned int u) {
    unsigned int b = (u & 0x80000000u) ? (u ^ 0x80000000u) : ~u;
    return __uint_as_float(b);
}
__device__ __forceinline__ unsigned long long u64max(unsigned long long a, unsigned long long b) {
    return a > b ? a : b;
}
__device__ __forceinline__ unsigned long long shfl_xor_u64(unsigned long long v, int mask) {
    unsigned int lo = (unsigned int)(v & 0xFFFFFFFFull);
    unsigned int hi = (unsigned int)(v >> 32);
    lo = __shfl_xor(lo, mask, 64);
    hi = __shfl_xor(hi, mask, 64);
    return ((unsigned long long)hi << 32) | (unsigned long long)lo;
}

// ---------------------------------------------------------------------------
// Kernel 0: transpose scores [B][N][91] -> [B][90][N] (classes 1..90 only)
// ---------------------------------------------------------------------------
__global__ __launch_bounds__(NTH) void transpose_k(const float* __restrict__ in,
                                                   float* __restrict__ out) {
    __shared__ float tile[64][93];  // pad 93: gcd(93,32)=1 -> conflict-free column reads
    const int tid = threadIdx.x;
    const int n0 = blockIdx.x * 64;
    const int b = blockIdx.y;
    const float* src = in + ((size_t)b * NBOX + n0) * NCLSIN;
    for (int t = tid; t < 64 * NCLSIN; t += NTH) {
        tile[t / NCLSIN][t % NCLSIN] = src[t];
    }
    __syncthreads();
    for (int t = tid; t < 64 * NCLS; t += NTH) {
        int c0 = t >> 6;       // 0..89
        int j = t & 63;
        out[((size_t)b * NCLS + c0) * NBOX + n0 + j] = tile[j][c0 + 1];
    }
}

// ---------------------------------------------------------------------------
// Kernel 1: one block per (batch, class): exact greedy NMS, 100 selections.
// ---------------------------------------------------------------------------
__global__ __launch_bounds__(NTH) void nms_k(const float* __restrict__ scores,
                                             const float4* __restrict__ boxes,
                                             float* __restrict__ ws_sc,
                                             float* __restrict__ ws_bx,
                                             int transposed) {
    __shared__ float masked[NBOX];                 // 64 KB
    __shared__ unsigned long long red[NTH / 64];
    const int tid = threadIdx.x;
    const int c0 = blockIdx.x;    // class-1 index, 0..89
    const int b = blockIdx.y;
    const int bc = b * NCLS + c0;

    float4* masked4 = reinterpret_cast<float4*>(masked);

    // load + score-threshold mask
    if (transposed) {
        const float* src = scores + (size_t)bc * NBOX;
        for (int i4 = tid; i4 < NBOX / 4; i4 += NTH) {
            float4 v = *reinterpret_cast<const float4*>(src + i4 * 4);
            float4 m;
            m.x = v.x > 0.3f ? v.x : NEGV;
            m.y = v.y > 0.3f ? v.y : NEGV;
            m.z = v.z > 0.3f ? v.z : NEGV;
            m.w = v.w > 0.3f ? v.w : NEGV;
            masked4[i4] = m;
        }
    } else {
        const float* src = scores + (size_t)b * NBOX * NCLSIN + (c0 + 1);
        for (int i = tid; i < NBOX; i += NTH) {
            float s = src[(size_t)i * NCLSIN];
            masked[i] = s > 0.3f ? s : NEGV;
        }
    }
    const float4* bbase = boxes + (size_t)b * NBOX;
    __syncthreads();

    for (int it = 0; it < MAXSEL; ++it) {
        // ---- argmax with first-index tie-break (key = score<<32 | ~idx) ----
        unsigned long long best = 0ull;
#pragma unroll
        for (int k = 0; k < NBOX / (NTH * 4); ++k) {
            int i4 = tid + k * NTH;
            float4 v = masked4[i4];
            int ib = i4 << 2;
            unsigned long long k0 = ((unsigned long long)fmap(v.x) << 32) | (0xFFFFFFFFu - ib);
            unsigned long long k1 = ((unsigned long long)fmap(v.y) << 32) | (0xFFFFFFFFu - (ib + 1));
            unsigned long long k2 = ((unsigned long long)fmap(v.z) << 32) | (0xFFFFFFFFu - (ib + 2));
            unsigned long long k3 = ((unsigned long long)fmap(v.w) << 32) | (0xFFFFFFFFu - (ib + 3));
            best = u64max(best, u64max(u64max(k0, k1), u64max(k2, k3)));
        }
#pragma unroll
        for (int off = 32; off > 0; off >>= 1) {
            best = u64max(best, shfl_xor_u64(best, off));
        }
        if ((tid & 63) == 0) red[tid >> 6] = best;
        __syncthreads();   // also orders: all masked reads done before suppression writes
        best = red[0];
#pragma unroll
        for (int w = 1; w < NTH / 64; ++w) best = u64max(best, red[w]);
        int idx = (int)(0xFFFFFFFFu - (unsigned int)(best & 0xFFFFFFFFull));
        float score = funmap((unsigned int)(best >> 32));

        if (!(score > NEGH)) {
            // invalid: every later step is also invalid -> zero-fill and stop
            for (int k2 = it + tid; k2 < MAXSEL; k2 += NTH) {
                ws_sc[(size_t)bc * MAXSEL + k2] = 0.f;
                float4 z = make_float4(0.f, 0.f, 0.f, 0.f);
                *reinterpret_cast<float4*>(ws_bx + ((size_t)bc * MAXSEL + k2) * 4) = z;
            }
            break;  // uniform across block (best came from shared red[])
        }

        float4 sb = bbase[idx];  // same address across lanes -> broadcast
        if (tid == 0) {
            ws_sc[(size_t)bc * MAXSEL + it] = score;
            *reinterpret_cast<float4*>(ws_bx + ((size_t)bc * MAXSEL + it) * 4) = sb;
        }
        // exact reference arithmetic: no FMA contraction, IEEE division
        float sarea = __fmul_rn(__fsub_rn(sb.z, sb.x), __fsub_rn(sb.w, sb.y));

        // ---- suppression sweep ----
#pragma unroll
        for (int k = 0; k < NBOX / (NTH * 4); ++k) {
            int i4 = tid + k * NTH;
            float4 m4 = masked4[i4];
            int ib = i4 << 2;
            float mv[4] = {m4.x, m4.y, m4.z, m4.w};
#pragma unroll
            for (int j = 0; j < 4; ++j) {
                int i = ib + j;
                if (mv[j] > NEGH) {
                    float4 bx = bbase[i];
                    float y1 = fmaxf(sb.x, bx.x);
                    float x1 = fmaxf(sb.y, bx.y);
                    float y2 = fminf(sb.z, bx.z);
                    float x2 = fminf(sb.w, bx.w);
                    float dy = fmaxf(__fsub_rn(y2, y1), 0.f);
                    float dx = fmaxf(__fsub_rn(x2, x1), 0.f);
                    float inter = __fmul_rn(dy, dx);
                    float ai = __fmul_rn(__fsub_rn(bx.z, bx.x), __fsub_rn(bx.w, bx.y));
                    float uni = __fsub_rn(__fadd_rn(sarea, ai), inter);
                    bool sup = (i == idx);
                    if (uni > 0.f) sup = sup || (__fdiv_rn(inter, uni) > 0.5f);
                    if (sup) masked[i] = NEGV;
                }
            }
        }
        __syncthreads();  // suppression writes visible before next argmax scan
    }
}

// ---------------------------------------------------------------------------
// Kernel 2: one block per batch: stable top-200 over the 9000 flat entries.
// ---------------------------------------------------------------------------
__global__ __launch_bounds__(NTH) void topk_k(const float* __restrict__ ws_sc,
                                              const float* __restrict__ ws_bx,
                                              float* __restrict__ out_sc,
                                              float* __restrict__ out_bx) {
    __shared__ unsigned long long keys[NCLS * MAXSEL];  // 9000 * 8B = 72 KB
    __shared__ unsigned long long red[NTH / 64];
    const int tid = threadIdx.x;
    const int b = blockIdx.x;

    for (int f = tid; f < NCLS * MAXSEL; f += NTH) {
        float s = ws_sc[(size_t)b * NCLS * MAXSEL + f];
        // scores are >= 0 -> raw bits are monotone; low word = ~flat for stable ties
        keys[f] = ((unsigned long long)__float_as_uint(s) << 32) | (0xFFFFFFFFu - f);
    }
    __syncthreads();

    for (int k = 0; k < TOPK; ++k) {
        unsigned long long best = 0ull;
        for (int f = tid; f < NCLS * MAXSEL; f += NTH) best = u64max(best, keys[f]);
#pragma unroll
        for (int off = 32; off > 0; off >>= 1) {
            best = u64max(best, shfl_xor_u64(best, off));
        }
        if ((tid & 63) == 0) red[tid >> 6] = best;
        __syncthreads();
        best = red[0];
#pragma unroll
        for (int w = 1; w < NTH / 64; ++w) best = u64max(best, red[w]);
        int flat = (int)(0xFFFFFFFFu - (unsigned int)(best & 0xFFFFFFFFull));
        float s = __uint_as_float((unsigned int)(best >> 32));
        if (tid == 0) {
            keys[flat] = 0ull;  // 0 < any real key (low word >= 0xFFFFDCD8)
            float cls = (s > 0.f) ? (float)(flat / MAXSEL + 1) : 0.f;
            out_sc[((size_t)b * TOPK + k) * 2 + 0] = cls;
            out_sc[((size_t)b * TOPK + k) * 2 + 1] = s;
            float4 bx = *reinterpret_cast<const float4*>(ws_bx + ((size_t)b * NCLS * MAXSEL + flat) * 4);
            *reinterpret_cast<float4*>(out_bx + ((size_t)b * TOPK + k) * 4) = bx;
        }
        __syncthreads();
    }
}

// ---------------------------------------------------------------------------
extern "C" void kernel_launch(void* const* d_in, const int* in_sizes, int n_in,
                              void* d_out, int out_size, void* d_ws, size_t ws_size,
                              hipStream_t stream) {
    const float* scores = (const float*)d_in[0];
    const float4* boxes = (const float4*)d_in[1];
    float* out = (float*)d_out;

    const int B = in_sizes[1] / (NBOX * 4);  // boxes_pred is [B, N, 4]

    size_t t_elems = (size_t)B * NCLS * NBOX;
    size_t sc_elems = (size_t)B * NCLS * MAXSEL;
    size_t bx_elems = sc_elems * 4;
    size_t need_t = (t_elems + sc_elems + bx_elems) * sizeof(float);

    float* ws_f = (float*)d_ws;
    bool use_t = ws_size >= need_t;
    float* ws_t = ws_f;
    float* ws_sc = use_t ? (ws_f + t_elems) : ws_f;
    float* ws_bx = ws_sc + sc_elems;

    if (use_t) {
        transpose_k<<<dim3(NBOX / 64, B), NTH, 0, stream>>>(scores, ws_t);
        nms_k<<<dim3(NCLS, B), NTH, 0, stream>>>(ws_t, boxes, ws_sc, ws_bx, 1);
    } else {
        nms_k<<<dim3(NCLS, B), NTH, 0, stream>>>(scores, boxes, ws_sc, ws_bx, 0);
    }
    topk_k<<<B, NTH, 0, stream>>>(ws_sc, ws_bx, out,
                                  out + (size_t)B * TOPK * 2);
}

// Round 2
// 206.794 us; speedup vs baseline: 55.6428x; 55.6428x over previous
//
#include <hip/hip_runtime.h>

#define NTH 256
#define NBOX 16384
#define NCLSIN 91
#define NCLS 90
#define MAXSEL 100
#define TOPK 200
#define TSEL 256      // candidates fetched per NMS band (>= ~110 typically walked)
#define CAP 1024      // candidate list capacity (overshoot margin)
#define CBCAP 512     // prefetched candidate boxes
#define BINS 2048
#define GRP 8         // BINS / NTH

// order-preserving fp32 <-> u32 (strictly monotone for all non-NaN)
__device__ __forceinline__ unsigned fmap(float f) {
    unsigned u = __float_as_uint(f);
    return (u & 0x80000000u) ? ~u : (u | 0x80000000u);
}
__device__ __forceinline__ float funmap(unsigned u) {
    unsigned b = (u & 0x80000000u) ? (u ^ 0x80000000u) : ~u;
    return __uint_as_float(b);
}

// exact reference IoU>0.5 test: selected box s (area sa) vs candidate c (area ca).
// Same op order as jax: inter = dy*dx; union = sa + ca - inter; inter/union > 0.5.
__device__ __forceinline__ bool sup_test(float4 s, float sa, float4 c, float ca) {
    float y1 = fmaxf(s.x, c.x);
    float x1 = fmaxf(s.y, c.y);
    float y2 = fminf(s.z, c.z);
    float x2 = fminf(s.w, c.w);
    float dy = fmaxf(__fsub_rn(y2, y1), 0.f);
    float dx = fmaxf(__fsub_rn(x2, x1), 0.f);
    float inter = __fmul_rn(dy, dx);
    float uni = __fsub_rn(__fadd_rn(sa, ca), inter);
    return (uni > 0.f) && (__fdiv_rn(inter, uni) > 0.5f);
}

// Given LDS hist[BINS] of eligible elements (bin ascending = key descending),
// find bstar = min bin with inclusive-prefix >= need (the need-th largest key's bin).
// Defaults to BINS-1 when prefix never reaches need (caller retries larger shift).
__device__ __forceinline__ void bin_select(unsigned* hist, unsigned* gbuf,
                                           int* sh_g, int* sh_b, unsigned* sh_pb,
                                           int tid, unsigned need) {
    unsigned gs = 0;
#pragma unroll
    for (int q = 0; q < GRP; ++q) gs += hist[tid * GRP + q];
    gbuf[tid] = gs;
    __syncthreads();
    for (int off = 1; off < NTH; off <<= 1) {   // inclusive prefix scan
        unsigned add = (tid >= off) ? gbuf[tid - off] : 0u;
        __syncthreads();
        gbuf[tid] += add;
        __syncthreads();
    }
    if (tid == 0) *sh_g = NTH - 1;
    __syncthreads();
    if (gbuf[tid] >= need && (tid == 0 || gbuf[tid - 1] < need)) *sh_g = tid;
    __syncthreads();
    if (tid == 0) {
        int g = *sh_g;
        unsigned acc = (g > 0) ? gbuf[g - 1] : 0u;
        int bs = g * GRP + (GRP - 1);
        unsigned pb = acc;
#pragma unroll
        for (int q = 0; q < GRP; ++q) {
            acc += hist[g * GRP + q];
            if (acc >= need) { bs = g * GRP + q; pb = acc; break; }
            pb = acc;
        }
        *sh_b = bs; *sh_pb = pb;
    }
    __syncthreads();
}

// ---------------------------------------------------------------------------
// Kernel 0: scores [B][N][91] -> keys [B][90][N]; 0 marks score <= 0.3
// ---------------------------------------------------------------------------
__global__ __launch_bounds__(NTH) void transpose_k(const float* __restrict__ in,
                                                   unsigned* __restrict__ out) {
    __shared__ float tile[64][93];  // pad 93: conflict-free column reads
    const int tid = threadIdx.x;
    const int n0 = blockIdx.x * 64;
    const int b = blockIdx.y;
    const float* src = in + ((size_t)b * NBOX + n0) * NCLSIN;
    for (int t = tid; t < 64 * NCLSIN; t += NTH) {
        tile[t / NCLSIN][t % NCLSIN] = src[t];
    }
    __syncthreads();
    for (int t = tid; t < 64 * NCLS; t += NTH) {
        int c0 = t >> 6;
        int j = t & 63;
        float s = tile[j][c0 + 1];
        out[((size_t)b * NCLS + c0) * NBOX + n0 + j] = (s > 0.3f) ? fmap(s) : 0u;
    }
}

__device__ __forceinline__ unsigned raw_key(const float* sraw, int i) {
    float s = sraw[(size_t)i * NCLSIN];
    return (s > 0.3f) ? fmap(s) : 0u;
}

// ---------------------------------------------------------------------------
// Kernel 1: one block per (batch, class). Exact greedy NMS via
// radix-select top-TSEL -> sort -> serial walk (IoU vs selected-in-registers).
// Refill-band loop preserves exactness if >TSEL candidates must be examined.
// ---------------------------------------------------------------------------
__global__ __launch_bounds__(NTH) void nms_k(const unsigned* __restrict__ keys,
                                             const float* __restrict__ scores_raw,
                                             const float4* __restrict__ boxes,
                                             float* __restrict__ ws_sc,
                                             float* __restrict__ ws_bx,
                                             int transposed) {
    __shared__ unsigned hist[BINS];              // 8 KB
    __shared__ unsigned gbuf[NTH];               // 1 KB
    __shared__ unsigned long long cand[CAP];     // 8 KB
    __shared__ float4 candbox[CBCAP];            // 8 KB
    __shared__ unsigned sh_kmax, sh_pb;
    __shared__ int sh_E, sh_g, sh_b, sh_cnt, sh_nsel;

    const int tid = threadIdx.x;
    const int c0 = blockIdx.x;
    const int b = blockIdx.y;
    const int bc = b * NCLS + c0;
    const unsigned* kcol = keys + (size_t)bc * NBOX;
    const float* sraw = scores_raw + (size_t)b * NBOX * NCLSIN + (c0 + 1);
    const float4* bbase = boxes + (size_t)b * NBOX;

    // walk state: selected boxes distributed in wave-0 registers (2 slots/lane)
    float4 sel0 = make_float4(0.f, 0.f, 0.f, 0.f);
    float4 sel1 = make_float4(0.f, 0.f, 0.f, 0.f);
    float sa0 = 0.f, sa1 = 0.f, ss0 = 0.f, ss1 = 0.f;
    int nsel = 0;
    unsigned long long lastk = ~0ull;

    for (;;) {
        // ---- pass 1: eligible count + max key ----
        unsigned km = 0, ce = 0;
        for (int i = tid; i < NBOX; i += NTH) {
            unsigned k = transposed ? kcol[i] : raw_key(sraw, i);
            if (k) {
                unsigned long long key =
                    ((unsigned long long)k << 32) | (0xFFFFFFFFu - (unsigned)i);
                if (key < lastk) { ce++; km = km > k ? km : k; }
            }
        }
#pragma unroll
        for (int off = 32; off > 0; off >>= 1) {
            unsigned o = (unsigned)__shfl_xor((int)km, off, 64);
            km = km > o ? km : o;
            ce += (unsigned)__shfl_xor((int)ce, off, 64);
        }
        if ((tid & 63) == 0) { gbuf[tid >> 6] = km; gbuf[8 + (tid >> 6)] = ce; }
        __syncthreads();
        if (tid == 0) {
            unsigned m2 = 0, c2 = 0;
            for (int w = 0; w < NTH / 64; ++w) {
                m2 = m2 > gbuf[w] ? m2 : gbuf[w];
                c2 += gbuf[8 + w];
            }
            sh_kmax = m2; sh_E = (int)c2;
        }
        __syncthreads();
        const int E = sh_E;
        const unsigned kmax = sh_kmax;
        if (E == 0) break;

        // ---- radix-select threshold for top-TSEL (distance-from-max bins) ----
        unsigned thr = 1u;
        if (E > TSEL) {
            for (int shift = 8;; shift += 4) {
                for (int i = tid; i < BINS; i += NTH) hist[i] = 0u;
                __syncthreads();
                for (int i = tid; i < NBOX; i += NTH) {
                    unsigned k = transposed ? kcol[i] : raw_key(sraw, i);
                    if (k) {
                        unsigned long long key =
                            ((unsigned long long)k << 32) | (0xFFFFFFFFu - (unsigned)i);
                        if (key < lastk) {
                            unsigned bin = (kmax - k) >> shift;
                            if (bin < BINS - 1) atomicAdd(&hist[bin], 1u);  // skip far tail: no hotspot
                        }
                    }
                }
                __syncthreads();
                bin_select(hist, gbuf, &sh_g, &sh_b, &sh_pb, tid, (unsigned)TSEL);
                const int bstar = sh_b;
                if (bstar < BINS - 1) {
                    long long t = (long long)kmax - ((long long)(bstar + 1) << shift) + 1;
                    thr = (t < 1) ? 1u : (unsigned)t;
                    break;
                }
                // crossing fell in clamped tail -> widen window, retry (exactness preserved)
            }
        }

        // ---- compaction ----
        if (tid == 0) sh_cnt = 0;
        __syncthreads();
        for (int i = tid; i < NBOX; i += NTH) {
            unsigned k = transposed ? kcol[i] : raw_key(sraw, i);
            if (k >= thr) {
                unsigned long long key =
                    ((unsigned long long)k << 32) | (0xFFFFFFFFu - (unsigned)i);
                if (key < lastk) {
                    int pos = atomicAdd(&sh_cnt, 1);
                    if (pos < CAP) cand[pos] = key;  // overflow impossible: overshoot ~ bin count
                }
            }
        }
        __syncthreads();
        const int M = sh_cnt < CAP ? sh_cnt : CAP;

        // ---- bitonic sort descending (pad with 0) ----
        int P = 1;
        while (P < M) P <<= 1;
        for (int i = M + tid; i < P; i += NTH) cand[i] = 0ull;
        __syncthreads();
        for (int kk = 2; kk <= P; kk <<= 1) {
            for (int jj = kk >> 1; jj > 0; jj >>= 1) {
                for (int i = tid; i < P; i += NTH) {
                    int ixj = i ^ jj;
                    if (ixj > i) {
                        unsigned long long a = cand[i], c = cand[ixj];
                        bool sw = ((i & kk) == 0) ? (a < c) : (a > c);
                        if (sw) { cand[i] = c; cand[ixj] = a; }
                    }
                }
                __syncthreads();
            }
        }

        // ---- prefetch candidate boxes (parallel gather) ----
        const int PBX = M < CBCAP ? M : CBCAP;
        for (int i = tid; i < PBX; i += NTH) {
            int idx = (int)(0xFFFFFFFFu - (unsigned)cand[i]);
            candbox[i] = bbase[idx];
        }
        __syncthreads();

        // ---- serial walk (wave 0), IoU vs selected parallel across lanes ----
        if (tid < 64) {
            for (int m = 0; m < M && nsel < MAXSEL; ++m) {
                unsigned long long key = cand[m];
                float4 bx = (m < CBCAP) ? candbox[m]
                                        : bbase[(int)(0xFFFFFFFFu - (unsigned)key)];
                float ca = __fmul_rn(__fsub_rn(bx.z, bx.x), __fsub_rn(bx.w, bx.y));
                bool sup = false;
                if (tid < nsel) sup = sup_test(sel0, sa0, bx, ca);
                if (tid + 64 < nsel) sup = sup || sup_test(sel1, sa1, bx, ca);
                if (!__any(sup)) {
                    if (tid == nsel) {
                        sel0 = bx; sa0 = ca; ss0 = funmap((unsigned)(key >> 32));
                    }
                    if (tid == nsel - 64) {
                        sel1 = bx; sa1 = ca; ss1 = funmap((unsigned)(key >> 32));
                    }
                    nsel++;
                }
            }
            if (tid == 0) sh_nsel = nsel;
        }
        __syncthreads();
        nsel = sh_nsel;
        if (nsel >= MAXSEL || E <= M) break;  // done, or all eligible examined
        lastk = cand[M - 1];                  // continue below this band (exact refill)
        __syncthreads();
    }

    // ---- outputs: selections in greedy order, zero-padded ----
    if (tid < 64) {
        float* scp = ws_sc + (size_t)bc * MAXSEL;
        float4* bxp = (float4*)(ws_bx + (size_t)bc * MAXSEL * 4);
        {
            bool v = tid < nsel;
            scp[tid] = v ? ss0 : 0.f;
            bxp[tid] = v ? sel0 : make_float4(0.f, 0.f, 0.f, 0.f);
        }
        int j1 = tid + 64;
        if (j1 < MAXSEL) {
            bool v = j1 < nsel;
            scp[j1] = v ? ss1 : 0.f;
            bxp[j1] = v ? sel1 : make_float4(0.f, 0.f, 0.f, 0.f);
        }
    }
}

// ---------------------------------------------------------------------------
// Kernel 2: one block per batch: stable top-200 of 9000 via radix-select+sort.
// Keys use raw float bits (scores >= 0 -> monotone); low word ~flat for ties.
// ---------------------------------------------------------------------------
__global__ __launch_bounds__(NTH) void topk_k(const float* __restrict__ ws_sc,
                                              const float* __restrict__ ws_bx,
                                              float* __restrict__ out_sc,
                                              float* __restrict__ out_bx) {
    __shared__ unsigned hist[BINS];
    __shared__ unsigned gbuf[NTH];
    __shared__ unsigned long long cand[CAP];
    __shared__ unsigned sh_kmax, sh_pb;
    __shared__ int sh_E, sh_g, sh_b, sh_cnt;

    const int tid = threadIdx.x;
    const int b = blockIdx.x;
    const int NF = NCLS * MAXSEL;  // 9000
    const float* sp = ws_sc + (size_t)b * NF;

    unsigned km = 0, ce = 0;
    for (int f = tid; f < NF; f += NTH) {
        unsigned k = __float_as_uint(sp[f]);
        if (k) { ce++; km = km > k ? km : k; }
    }
#pragma unroll
    for (int off = 32; off > 0; off >>= 1) {
        unsigned o = (unsigned)__shfl_xor((int)km, off, 64);
        km = km > o ? km : o;
        ce += (unsigned)__shfl_xor((int)ce, off, 64);
    }
    if ((tid & 63) == 0) { gbuf[tid >> 6] = km; gbuf[8 + (tid >> 6)] = ce; }
    __syncthreads();
    if (tid == 0) {
        unsigned m2 = 0, c2 = 0;
        for (int w = 0; w < NTH / 64; ++w) {
            m2 = m2 > gbuf[w] ? m2 : gbuf[w];
            c2 += gbuf[8 + w];
        }
        sh_kmax = m2; sh_E = (int)c2;
    }
    __syncthreads();
    const int E = sh_E;
    const unsigned kmax = sh_kmax;

    unsigned thr = 1u;
    if (E > TOPK) {
        for (int shift = 4;; shift += 4) {
            for (int i = tid; i < BINS; i += NTH) hist[i] = 0u;
            __syncthreads();
            for (int f = tid; f < NF; f += NTH) {
                unsigned k = __float_as_uint(sp[f]);
                if (k) {
                    unsigned bin = (kmax - k) >> shift;
                    if (bin < BINS - 1) atomicAdd(&hist[bin], 1u);
                }
            }
            __syncthreads();
            bin_select(hist, gbuf, &sh_g, &sh_b, &sh_pb, tid, (unsigned)TOPK);
            const int bstar = sh_b;
            if (bstar < BINS - 1) {
                long long t = (long long)kmax - ((long long)(bstar + 1) << shift) + 1;
                thr = (t < 1) ? 1u : (unsigned)t;
                break;
            }
        }
    }

    if (tid == 0) sh_cnt = 0;
    __syncthreads();
    for (int f = tid; f < NF; f += NTH) {
        unsigned k = __float_as_uint(sp[f]);
        if (k >= thr) {
            int pos = atomicAdd(&sh_cnt, 1);
            if (pos < CAP)
                cand[pos] = ((unsigned long long)k << 32) | (0xFFFFFFFFu - (unsigned)f);
        }
    }
    __syncthreads();
    int M = sh_cnt < CAP ? sh_cnt : CAP;

    if (M < TOPK) {
        // fewer than 200 positives: pad with zero-score entries, smallest flat
        // index first (stable tie-break). Enough zeros exist among f < M+TOPK.
        int lim = M + TOPK;
        if (lim > NF) lim = NF;
        for (int f = tid; f < lim; f += NTH) {
            unsigned k = __float_as_uint(sp[f]);
            if (k == 0) {
                int pos = atomicAdd(&sh_cnt, 1);
                if (pos < CAP)
                    cand[pos] = (unsigned long long)(0xFFFFFFFFu - (unsigned)f);
            }
        }
        __syncthreads();
        M = sh_cnt < CAP ? sh_cnt : CAP;
    }

    int P = 1;
    while (P < M) P <<= 1;
    for (int i = M + tid; i < P; i += NTH) cand[i] = 0ull;
    __syncthreads();
    for (int kk = 2; kk <= P; kk <<= 1) {
        for (int jj = kk >> 1; jj > 0; jj >>= 1) {
            for (int i = tid; i < P; i += NTH) {
                int ixj = i ^ jj;
                if (ixj > i) {
                    unsigned long long a = cand[i], c = cand[ixj];
                    bool sw = ((i & kk) == 0) ? (a < c) : (a > c);
                    if (sw) { cand[i] = c; cand[ixj] = a; }
                }
            }
            __syncthreads();
        }
    }

    for (int k = tid; k < TOPK; k += NTH) {
        float cls = 0.f, s = 0.f;
        float4 bx = make_float4(0.f, 0.f, 0.f, 0.f);
        if (k < M) {
            unsigned long long key = cand[k];
            unsigned f = 0xFFFFFFFFu - (unsigned)key;
            s = __uint_as_float((unsigned)(key >> 32));
            cls = (s > 0.f) ? (float)(f / MAXSEL + 1) : 0.f;
            bx = *(const float4*)(ws_bx + ((size_t)b * NF + f) * 4);
        }
        out_sc[((size_t)b * TOPK + k) * 2 + 0] = cls;
        out_sc[((size_t)b * TOPK + k) * 2 + 1] = s;
        ((float4*)out_bx)[(size_t)b * TOPK + k] = bx;
    }
}

// ---------------------------------------------------------------------------
extern "C" void kernel_launch(void* const* d_in, const int* in_sizes, int n_in,
                              void* d_out, int out_size, void* d_ws, size_t ws_size,
                              hipStream_t stream) {
    const float* scores = (const float*)d_in[0];
    const float4* boxes = (const float4*)d_in[1];
    float* out = (float*)d_out;

    const int B = in_sizes[1] / (NBOX * 4);  // boxes_pred is [B, N, 4]

    size_t t_elems = (size_t)B * NCLS * NBOX;
    size_t sc_elems = (size_t)B * NCLS * MAXSEL;
    size_t bx_elems = sc_elems * 4;
    size_t need_t = (t_elems + sc_elems + bx_elems) * 4;

    bool use_t = ws_size >= need_t;
    unsigned* ws_t = (unsigned*)d_ws;
    float* ws_sc = use_t ? ((float*)d_ws + t_elems) : (float*)d_ws;
    float* ws_bx = ws_sc + sc_elems;

    if (use_t) {
        transpose_k<<<dim3(NBOX / 64, B), NTH, 0, stream>>>(scores, ws_t);
    }
    nms_k<<<dim3(NCLS, B), NTH, 0, stream>>>(ws_t, scores, boxes, ws_sc, ws_bx,
                                             use_t ? 1 : 0);
    topk_k<<<B, NTH, 0, stream>>>(ws_sc, ws_bx, out, out + (size_t)B * TOPK * 2);
}